// Round 1
// baseline (2349.117 us; speedup 1.0000x reference)
//
#include <hip/hip_runtime.h>

// ---------------------------------------------------------------------------
// Model: SAGE-GCN LSTM (SMPL kinematic tree), N=1024, J=24, D=64
//   24 sequential LSTM cells; each cell = one [24576 x 256] @ [256 x 256] GEMM
//   (v = [agg(x), x, agg(h), h]) + elementwise gate math, then 12 per-step
//   decode GEMMs [1024 x 1536] @ [1536 x 72].
// Round 0: fp32 correctness baseline. Fused per-n cell kernel.
// ---------------------------------------------------------------------------

#define NBATCH 1024
#define NJNT   24
#define NDIM   64
#define NJD    (NBATCH * NJNT * NDIM)   // 1,572,864 floats per state tensor

// SMPL kinematic tree: undirected + self-loops, row-normalized (mean aggr).
__constant__ int c_nbr[24][5] = {
  {0,1,2,3,-1},  {1,0,4,-1,-1}, {2,0,5,-1,-1}, {3,0,6,-1,-1},
  {4,1,7,-1,-1}, {5,2,8,-1,-1}, {6,3,9,-1,-1}, {7,4,10,-1,-1},
  {8,5,11,-1,-1},{9,6,12,13,14},{10,7,-1,-1,-1},{11,8,-1,-1,-1},
  {12,9,15,-1,-1},{13,9,16,-1,-1},{14,9,17,-1,-1},{15,12,-1,-1,-1},
  {16,13,18,-1,-1},{17,14,19,-1,-1},{18,16,20,-1,-1},{19,17,21,-1,-1},
  {20,18,22,-1,-1},{21,19,23,-1,-1},{22,20,-1,-1,-1},{23,21,-1,-1,-1}
};
__constant__ float c_invdeg[24] = {
  0.25f, 1.f/3.f, 1.f/3.f, 1.f/3.f, 1.f/3.f, 1.f/3.f, 1.f/3.f, 1.f/3.f,
  1.f/3.f, 0.2f, 0.5f, 0.5f, 1.f/3.f, 1.f/3.f, 1.f/3.f, 0.5f,
  1.f/3.f, 1.f/3.f, 1.f/3.f, 1.f/3.f, 1.f/3.f, 1.f/3.f, 0.5f, 0.5f
};

__device__ __forceinline__ float sigm_(float x) { return 1.0f / (1.0f + __expf(-x)); }
__device__ __forceinline__ float tanh_(float x) { return 2.0f / (1.0f + __expf(-2.0f * x)) - 1.0f; }

// ---------------------------------------------------------------------------
// Build W_cat transposed [col(256)][k(256)] and fused bias[256].
//   col = g*64 + d (g in {I,F,T,O}), k = q*64 + kk with
//   q0: Wl[2g] (agg-x), q1: Wr[2g] (x), q2: Wl[2g+1] (agg-h), q3: Wr[2g+1] (h)
//   bias[col] = sage_bl[2g][d] + sage_bl[2g+1][d] + gate_b[g][d]
// ---------------------------------------------------------------------------
__global__ void prep_kernel(const float* __restrict__ sWl,
                            const float* __restrict__ sbl,
                            const float* __restrict__ sWr,
                            const float* __restrict__ gb,
                            float* __restrict__ Wcat,
                            float* __restrict__ bias)
{
  int idx = blockIdx.x * 256 + threadIdx.x;     // 65536 total
  int col = idx >> 8, k = idx & 255;
  int g = col >> 6, d = col & 63;
  int q = k >> 6, kk = k & 63;
  int i = 2 * g + (q >> 1);
  const float* Wsrc = (q & 1) ? sWr : sWl;
  Wcat[idx] = Wsrc[(i * 64 + kk) * 64 + d];
  if (blockIdx.x == 0) {
    int t = threadIdx.x;
    int gg = t >> 6, dd = t & 63;
    bias[t] = sbl[(2 * gg) * 64 + dd] + sbl[(2 * gg + 1) * 64 + dd] + gb[t];
  }
}

// ---------------------------------------------------------------------------
// Encoder: x[n,j,d] = relu(sum_a frame[n, j*3+a] * enc_W[a,d] + enc_b[d])
// ---------------------------------------------------------------------------
__global__ void enc_kernel(const float* __restrict__ frame_base, int frame_stride,
                           const float* __restrict__ eW, const float* __restrict__ eb,
                           float* __restrict__ xout)
{
  int idx = blockIdx.x * 256 + threadIdx.x;     // < NJD
  int n = idx / (NJNT * NDIM);
  int r = idx - n * (NJNT * NDIM);
  int j = r >> 6, d = r & 63;
  const float* f = frame_base + (long)n * frame_stride + j * 3;
  float v = eb[d] + f[0] * eW[d] + f[1] * eW[64 + d] + f[2] * eW[128 + d];
  xout[idx] = fmaxf(v, 0.0f);
}

// ---------------------------------------------------------------------------
// Fused LSTM cell, one block per batch element n.
//   LDS: xs/hs (6KB each) + union{ vT[j][256] (24KB) , pre[col][25] (25.6KB) }
//   -> 37.9 KB => 4 blocks/CU, 1024 blocks in one pass.
// Thread t owns output column col=t (g = t>>6, d = t&63), 24 fp32 accumulators.
// ---------------------------------------------------------------------------
__global__ __launch_bounds__(256) void cell_kernel(
    const float* __restrict__ x,
    float* __restrict__ hbuf,
    float* __restrict__ cbuf,
    const float* __restrict__ gw,     // gate_w [3][64]
    const float* __restrict__ Wcat,   // [col][k]
    const float* __restrict__ bias,   // [256]
    float* __restrict__ obuf)
{
  __shared__ float xs[NJNT * NDIM];
  __shared__ float hs[NJNT * NDIM];
  __shared__ __align__(16) float un[256 * 25];   // vT (6144 floats) / pre (6400 floats)

  const int n = blockIdx.x;
  const int t = threadIdx.x;
  const int base = n * (NJNT * NDIM);

  // phase 1: stage x, h
  #pragma unroll
  for (int i = 0; i < 6; ++i) {
    xs[t + i * 256] = x[base + t + i * 256];
    hs[t + i * 256] = hbuf[base + t + i * 256];
  }
  __syncthreads();

  // phase 2: build vT[j][k] = [agg(x) | x | agg(h) | h], k = q*64+dd
  const int q = t >> 6, dd = t & 63;
  for (int j = 0; j < NJNT; ++j) {
    float val;
    if (q == 0 || q == 2) {
      const float* s = (q == 0) ? xs : hs;
      float a = 0.0f;
      #pragma unroll
      for (int m = 0; m < 5; ++m) {
        int nb = c_nbr[j][m];
        if (nb >= 0) a += s[nb * 64 + dd];
      }
      val = a * c_invdeg[j];
    } else {
      val = (q == 1) ? xs[j * 64 + dd] : hs[j * 64 + dd];
    }
    un[j * 256 + t] = val;
  }
  __syncthreads();

  // phase 3: GEMM column dot. acc[j] = bias + sum_k vT[j][k] * Wcat[col][k]
  float acc[NJNT];
  const float bv = bias[t];
  #pragma unroll
  for (int j = 0; j < NJNT; ++j) acc[j] = bv;

  const float4* Wp = (const float4*)(Wcat + t * 256);
  for (int k4 = 0; k4 < 64; ++k4) {
    float4 w = Wp[k4];
    #pragma unroll
    for (int j = 0; j < NJNT; ++j) {
      float4 v = *((const float4*)(un + j * 256) + k4);
      acc[j] = fmaf(v.x, w.x, acc[j]);
      acc[j] = fmaf(v.y, w.y, acc[j]);
      acc[j] = fmaf(v.z, w.z, acc[j]);
      acc[j] = fmaf(v.w, w.w, acc[j]);
    }
  }
  __syncthreads();

  // phase 4: exchange pre-activations: pre[col][j], stride 25 (conflict-free)
  #pragma unroll
  for (int j = 0; j < NJNT; ++j) un[t * 25 + j] = acc[j];
  __syncthreads();

  // phase 5: LSTM gate epilogue over 1536 elements (6 per thread)
  const float gw0 = gw[dd], gw1 = gw[64 + dd], gw2 = gw[128 + dd];
  #pragma unroll
  for (int i = 0; i < 6; ++i) {
    int idx = i * 256 + t;
    int j = idx >> 6;                 // = i*4 + q
    float cv = cbuf[base + idx];
    float pI = un[(dd)       * 25 + j];
    float pF = un[(64 + dd)  * 25 + j];
    float pT = un[(128 + dd) * 25 + j];
    float pO = un[(192 + dd) * 25 + j];
    float Iv = sigm_(pI + gw0 * cv);
    float Fv = sigm_(pF + gw1 * cv);
    float Tv = tanh_(pT);
    float cn = Fv * cv + Iv * Tv;
    float Ov = sigm_(pO + gw2 * cn);
    float hn = Ov * tanh_(cn);
    obuf[base + idx] = Ov;
    hbuf[base + idx] = hn;
    cbuf[base + idx] = cn;
  }
}

// ---------------------------------------------------------------------------
// Per-step decoder: out[n, t, e] = O[n, :] . dec_W[:, e] + dec_b[e]
// block per n; 3 K-slices x 72 cols = 216 active threads; LDS reduce.
// ---------------------------------------------------------------------------
__global__ __launch_bounds__(256) void dec_kernel(
    const float* __restrict__ obuf, const float* __restrict__ dW,
    const float* __restrict__ db, float* __restrict__ out, int tstep)
{
  __shared__ float orow[1536];
  __shared__ float part[216];
  const int n = blockIdx.x, t = threadIdx.x;
  #pragma unroll
  for (int i = 0; i < 6; ++i) orow[t + i * 256] = obuf[n * 1536 + t + i * 256];
  __syncthreads();
  if (t < 216) {
    int s = t / 72, e = t - s * 72;
    int k0 = s * 512;
    float a = 0.0f;
    for (int k = k0; k < k0 + 512; ++k) a = fmaf(orow[k], dW[k * 72 + e], a);
    part[t] = a;
  }
  __syncthreads();
  if (t < 72) out[n * 864 + tstep * 72 + t] = part[t] + part[72 + t] + part[144 + t] + db[t];
}

// ---------------------------------------------------------------------------
extern "C" void kernel_launch(void* const* d_in, const int* in_sizes, int n_in,
                              void* d_out, int out_size, void* d_ws, size_t ws_size,
                              hipStream_t stream) {
  const float* src  = (const float*)d_in[0];   // [1024,16,72]
  const float* tgt  = (const float*)d_in[1];   // [1024,12,72]
  const float* encW = (const float*)d_in[2];   // [3,64]
  const float* encb = (const float*)d_in[3];   // [64]
  const float* sWl  = (const float*)d_in[4];   // [8,64,64]
  const float* sbl  = (const float*)d_in[5];   // [8,64]
  const float* sWr  = (const float*)d_in[6];   // [8,64,64]
  const float* gw   = (const float*)d_in[7];   // [3,1,64]
  const float* gb   = (const float*)d_in[8];   // [4,1,64]
  const float* dW   = (const float*)d_in[9];   // [1536,72]
  const float* db   = (const float*)d_in[10];  // [72]
  float* out = (float*)d_out;

  float* ws = (float*)d_ws;
  float* fA   = ws;                 // x / O ping
  float* fB   = ws + (size_t)NJD;   // x / O pong
  float* hb   = ws + 2 * (size_t)NJD;
  float* cb   = ws + 3 * (size_t)NJD;
  float* Wcat = ws + 4 * (size_t)NJD;      // 65536 floats
  float* bias = Wcat + 65536;              // 256 floats

  hipMemsetAsync(hb, 0, 2 * (size_t)NJD * sizeof(float), stream);  // h = c = 0
  prep_kernel<<<256, 256, 0, stream>>>(sWl, sbl, sWr, gb, Wcat, bias);

  // warm-up starts at src frame index T_src-12 = 4
  enc_kernel<<<NJD / 256, 256, 0, stream>>>(src + 4 * 72, 16 * 72, encW, encb, fA);

  for (int step = 0; step < 24; ++step) {
    float* in = (step & 1) ? fB : fA;
    float* ob = (step & 1) ? fA : fB;
    if (step == 12) {
      // decode init: re-encode tgt[:, 0] (warm-up's last output is discarded)
      enc_kernel<<<NJD / 256, 256, 0, stream>>>(tgt, 12 * 72, encW, encb, in);
    }
    cell_kernel<<<NBATCH, 256, 0, stream>>>(in, hb, cb, gw, Wcat, bias, ob);
    if (step >= 12) {
      dec_kernel<<<NBATCH, 256, 0, stream>>>(ob, dW, db, out, step - 12);
    }
  }
}

// Round 2
// 596.849 us; speedup vs baseline: 3.9359x; 3.9359x over previous
//
#include <hip/hip_runtime.h>

// ---------------------------------------------------------------------------
// SAGE-GCN LSTM, N=1024, J=24, D=64. Mono-kernel design:
//   - 1 block per batch element n, 512 threads (8 waves), runs all 24 cells.
//   - per step: GEMM [32x256]@[256x256] via v_mfma_f32_32x32x16_bf16.
//     Wave w owns cols [32w,32w+32); its B-slice lives in 64 VGPRs (persistent
//     across all 24 steps). A-tile (v) packed in LDS in MFMA fragment layout.
//   - c-state fp32 in registers; h/x bf16 in LDS; gates via LDS exchange.
//   - O (bf16) -> ws; final decode GEMM kernel; prep kernel packs weights.
// ---------------------------------------------------------------------------

typedef __bf16 bf16x8 __attribute__((ext_vector_type(8)));
typedef float f32x16 __attribute__((ext_vector_type(16)));

__constant__ int c_nbr[24][5] = {
  {0,1,2,3,-1},  {1,0,4,-1,-1}, {2,0,5,-1,-1}, {3,0,6,-1,-1},
  {4,1,7,-1,-1}, {5,2,8,-1,-1}, {6,3,9,-1,-1}, {7,4,10,-1,-1},
  {8,5,11,-1,-1},{9,6,12,13,14},{10,7,-1,-1,-1},{11,8,-1,-1,-1},
  {12,9,15,-1,-1},{13,9,16,-1,-1},{14,9,17,-1,-1},{15,12,-1,-1,-1},
  {16,13,18,-1,-1},{17,14,19,-1,-1},{18,16,20,-1,-1},{19,17,21,-1,-1},
  {20,18,22,-1,-1},{21,19,23,-1,-1},{22,20,-1,-1,-1},{23,21,-1,-1,-1}
};
__constant__ float c_invdeg[24] = {
  0.25f, 1.f/3.f, 1.f/3.f, 1.f/3.f, 1.f/3.f, 1.f/3.f, 1.f/3.f, 1.f/3.f,
  1.f/3.f, 0.2f, 0.5f, 0.5f, 1.f/3.f, 1.f/3.f, 1.f/3.f, 0.5f,
  1.f/3.f, 1.f/3.f, 1.f/3.f, 1.f/3.f, 1.f/3.f, 1.f/3.f, 0.5f, 0.5f
};

__device__ __forceinline__ unsigned short f2b(float f) {   // fp32 -> bf16 RNE
  unsigned int u = __float_as_uint(f);
  u += 0x7fffu + ((u >> 16) & 1u);
  return (unsigned short)(u >> 16);
}
__device__ __forceinline__ float b2f_lo(unsigned int u) { return __uint_as_float(u << 16); }
__device__ __forceinline__ float b2f_hi(unsigned int u) { return __uint_as_float(u & 0xffff0000u); }
__device__ __forceinline__ float sigm_(float x) { return 1.0f / (1.0f + __expf(-x)); }
__device__ __forceinline__ float tanh_(float x) { return 2.0f / (1.0f + __expf(-2.0f * x)) - 1.0f; }

// xs/hs state layout: row j (24), 64 bf16, XOR-swizzled in 16B chunks to break
// the stride-128B bank pattern on aggregation reads.
__device__ __forceinline__ int xh_idx(int j, int dd) {           // scalar elem
  return j * 64 + ((((dd >> 3) ^ (j & 7))) << 3) + (dd & 7);
}
__device__ __forceinline__ int xh_c(int j, int d8) {             // 8-elem chunk
  return j * 64 + ((d8 ^ (j & 7)) << 3);
}

// ---------------------------------------------------------------------------
// prep: pack weights.
//  Wfrag[w][t][lane][i] bf16 : B-fragment layout, col=32w+(lane&31),
//                              k = t*16 + (lane>>5)*8 + i, k = q*64+kk with
//                              q0:Wl[2g] q1:Wr[2g] q2:Wl[2g+1] q3:Wr[2g+1]
//  biasv[col] = sbl[2g][d] + sbl[2g+1][d] + gb[g][d]
//  dWT[e][k] bf16 = dec_W[k][e]
// ---------------------------------------------------------------------------
__global__ void prep2_kernel(const float* __restrict__ sWl, const float* __restrict__ sbl,
                             const float* __restrict__ sWr, const float* __restrict__ gb,
                             const float* __restrict__ dW,
                             unsigned short* __restrict__ Wfrag,
                             float* __restrict__ biasv,
                             unsigned short* __restrict__ dWT)
{
  int id = blockIdx.x * 256 + threadIdx.x;     // 176384 total
  if (id < 65536) {
    int i = id & 7, l = (id >> 3) & 63, t = (id >> 9) & 15, w = id >> 13;
    int k = t * 16 + ((l >> 5) << 3) + i;
    int col = w * 32 + (l & 31);
    int g = col >> 6, d = col & 63;
    int q = k >> 6, kk = k & 63;
    const float* Ws = (q & 1) ? sWr : sWl;
    float v = Ws[((2 * g + (q >> 1)) * 64 + kk) * 64 + d];
    Wfrag[id] = f2b(v);
  } else if (id < 65792) {
    int col = id - 65536;
    int g = col >> 6, dd = col & 63;
    biasv[col] = sbl[(2 * g) * 64 + dd] + sbl[(2 * g + 1) * 64 + dd] + gb[col];
  } else {
    int p = id - 65792;                        // < 110592
    int e = p / 1536, k = p - e * 1536;
    dWT[p] = f2b(dW[k * 72 + e]);
  }
}

// ---------------------------------------------------------------------------
// mono: all 24 cells for one batch element.
// ---------------------------------------------------------------------------
__global__ __launch_bounds__(512, 1) void mono_kernel(
    const float* __restrict__ src, const float* __restrict__ tgt,
    const float* __restrict__ encW, const float* __restrict__ encb,
    const float* __restrict__ gw,
    const unsigned short* __restrict__ Wfrag,
    const float* __restrict__ biasv,
    unsigned short* __restrict__ obuf)
{
  __shared__ __align__(16) unsigned short Afrag[16 * 64 * 8];  // 16 KB, frag layout
  __shared__ float pre[256 * 33];                              // 33.8 KB, [col][row]
  __shared__ __align__(16) unsigned short xs[24 * 64];         // 3 KB (swizzled)
  __shared__ __align__(16) unsigned short hs[24 * 64];         // 3 KB (swizzled)

  const int tid = threadIdx.x;
  const int n = blockIdx.x;
  const int w = tid >> 6, l = tid & 63;      // wave / lane (GEMM roles)
  const int d = tid & 63, j0 = tid >> 6;     // epilogue roles

  // ---- persistent B fragments: 16 x bf16x8 = 64 VGPRs -------------------
  bf16x8 Breg[16];
  {
    const bf16x8* wf = reinterpret_cast<const bf16x8*>(Wfrag) + w * 1024 + l;
    #pragma unroll
    for (int t = 0; t < 16; ++t) Breg[t] = wf[t * 64];
  }
  const float bv = biasv[w * 32 + (l & 31)];
  const float g0 = gw[d], g1 = gw[64 + d], g2 = gw[128 + d];
  float creg[3] = {0.0f, 0.0f, 0.0f};        // c-state, fp32, j = j0, j0+8, j0+16

  // zero h state and the A-tile pad lanes (rows 24..31)
  for (int i = tid; i < 768; i += 512) reinterpret_cast<unsigned int*>(hs)[i] = 0u;
  if (tid < 256) {
    int tt = tid >> 4, li = tid & 15;
    int lane = 24 + (li & 7) + ((li >> 3) << 5);
    *reinterpret_cast<uint4*>(Afrag + (tt * 64 + lane) * 8) = make_uint4(0, 0, 0, 0);
  }

  auto enc_to_xs = [&](const float* frame) {
    #pragma unroll
    for (int i = 0; i < 3; ++i) {
      int idx = tid + i * 512;
      int jj = idx >> 6, dd = idx & 63;
      const float* f = frame + jj * 3;
      float v = encb[dd] + f[0] * encW[dd] + f[1] * encW[64 + dd] + f[2] * encW[128 + dd];
      xs[xh_idx(jj, dd)] = f2b(fmaxf(v, 0.0f));
    }
  };

  enc_to_xs(src + (size_t)n * 1152 + 288);   // warm-up starts at src frame 4
  __syncthreads();

  for (int step = 0; step < 24; ++step) {
    if (step == 12) {                        // decode init: re-encode tgt[:,0]
      enc_to_xs(tgt + (size_t)n * 864);
      __syncthreads();
    }

    // ---- v-build: write A-tile (fragment layout, bf16) ------------------
    if (tid < 384) {                         // agg sections q0 (x), q2 (h)
      int sec = tid >= 192;
      int c = sec ? tid - 192 : tid;
      int jj = c >> 3, d8 = c & 7;
      const unsigned short* sb = sec ? hs : xs;
      float s0 = 0, s1 = 0, s2 = 0, s3 = 0, s4 = 0, s5 = 0, s6 = 0, s7 = 0;
      #pragma unroll
      for (int m = 0; m < 5; ++m) {
        int v = c_nbr[jj][m];
        if (v >= 0) {
          uint4 u = *reinterpret_cast<const uint4*>(sb + xh_c(v, d8));
          s0 += b2f_lo(u.x); s1 += b2f_hi(u.x);
          s2 += b2f_lo(u.y); s3 += b2f_hi(u.y);
          s4 += b2f_lo(u.z); s5 += b2f_hi(u.z);
          s6 += b2f_lo(u.w); s7 += b2f_hi(u.w);
        }
      }
      float sc = c_invdeg[jj];
      uint4 o;
      o.x = (unsigned)f2b(s0 * sc) | ((unsigned)f2b(s1 * sc) << 16);
      o.y = (unsigned)f2b(s2 * sc) | ((unsigned)f2b(s3 * sc) << 16);
      o.z = (unsigned)f2b(s4 * sc) | ((unsigned)f2b(s5 * sc) << 16);
      o.w = (unsigned)f2b(s6 * sc) | ((unsigned)f2b(s7 * sc) << 16);
      int k = (sec ? 128 : 0) + d8 * 8;
      int tt = k >> 4, hi = (k >> 3) & 1;
      *reinterpret_cast<uint4*>(Afrag + (tt * 64 + jj + (hi << 5)) * 8) = o;
    }
    if (tid >= 128) {                        // copy sections q1 (x), q3 (h)
      int c = tid - 128;
      int sec = c >= 192;
      int cc = sec ? c - 192 : c;
      int jj = cc >> 3, d8 = cc & 7;
      const unsigned short* sb = sec ? hs : xs;
      uint4 u = *reinterpret_cast<const uint4*>(sb + xh_c(jj, d8));
      int k = (sec ? 192 : 64) + d8 * 8;
      int tt = k >> 4, hi = (k >> 3) & 1;
      *reinterpret_cast<uint4*>(Afrag + (tt * 64 + jj + (hi << 5)) * 8) = u;
    }
    __syncthreads();

    // ---- GEMM: 16 x mfma_f32_32x32x16_bf16, B resident in VGPRs ---------
    f32x16 acc;
    #pragma unroll
    for (int r = 0; r < 16; ++r) acc[r] = bv;
    {
      const bf16x8* Ap = reinterpret_cast<const bf16x8*>(Afrag) + l;
      #pragma unroll
      for (int t = 0; t < 16; ++t) {
        bf16x8 a = Ap[t * 64];
        acc = __builtin_amdgcn_mfma_f32_32x32x16_bf16(a, Breg[t], acc, 0, 0, 0);
      }
    }
    {
      const int col33 = (w * 32 + (l & 31)) * 33;
      const int hi4 = (l >> 5) << 2;
      #pragma unroll
      for (int r = 0; r < 16; ++r) {
        int row = (r & 3) + ((r >> 2) << 3) + hi4;   // verified C/D mapping
        pre[col33 + row] = acc[r];
      }
    }
    __syncthreads();

    // ---- epilogue: gates, c/h update, publish x=O, h --------------------
    #pragma unroll
    for (int i = 0; i < 3; ++i) {
      int jj = j0 + (i << 3);
      int idx = (jj << 6) + d;
      float pI = pre[d * 33 + jj];
      float pF = pre[(64 + d) * 33 + jj];
      float pT = pre[(128 + d) * 33 + jj];
      float pO = pre[(192 + d) * 33 + jj];
      float cv = creg[i];
      float I = sigm_(pI + g0 * cv);
      float F = sigm_(pF + g1 * cv);
      float T = tanh_(pT);
      float cn = F * cv + I * T;
      float O = sigm_(pO + g2 * cn);
      float h = O * tanh_(cn);
      creg[i] = cn;
      unsigned short ob = f2b(O);
      int sw = xh_idx(jj, d);
      xs[sw] = ob;
      hs[sw] = f2b(h);
      if (step >= 12) obuf[(size_t)(n * 12 + step - 12) * 1536 + idx] = ob;
    }
    __syncthreads();
  }
}

// ---------------------------------------------------------------------------
// decode: out[row][e] = sum_k O[row][k] * dWT[e][k] + db[e], row = n*12+t.
// 16 rows per block; O rows staged in LDS (padded stride), dWT streamed (L2).
// ---------------------------------------------------------------------------
__global__ __launch_bounds__(256) void dec2_kernel(
    const unsigned short* __restrict__ obuf,
    const unsigned short* __restrict__ dWT,
    const float* __restrict__ db,
    float* __restrict__ out)
{
  __shared__ __align__(16) unsigned short orow[16 * 1544];
  const int tid = threadIdx.x;
  const size_t r0 = (size_t)blockIdx.x * 16;
  {
    const unsigned int* srcu = reinterpret_cast<const unsigned int*>(obuf + r0 * 1536);
    #pragma unroll
    for (int i = 0; i < 48; ++i) {
      int uid = tid + i * 256;                 // 12288 uints = 16 x 768
      int row = uid / 768, kk = uid - row * 768;
      reinterpret_cast<unsigned int*>(orow)[row * 772 + kk] = srcu[uid];
    }
  }
  __syncthreads();
  const int r = tid >> 4, c = tid & 15;
  const unsigned short* orp = orow + r * 1544;
  float acc[5] = {0, 0, 0, 0, 0};
  for (int k8 = 0; k8 < 192; ++k8) {
    uint4 ua = *reinterpret_cast<const uint4*>(orp + (k8 << 3));
    float x0 = b2f_lo(ua.x), x1 = b2f_hi(ua.x);
    float x2 = b2f_lo(ua.y), x3 = b2f_hi(ua.y);
    float x4 = b2f_lo(ua.z), x5 = b2f_hi(ua.z);
    float x6 = b2f_lo(ua.w), x7 = b2f_hi(ua.w);
    #pragma unroll
    for (int ei = 0; ei < 5; ++ei) {
      int e = c + (ei << 4);
      if (e < 72) {
        uint4 uw = *reinterpret_cast<const uint4*>(dWT + (size_t)e * 1536 + (k8 << 3));
        float a = acc[ei];
        a = fmaf(x0, b2f_lo(uw.x), a);
        a = fmaf(x1, b2f_hi(uw.x), a);
        a = fmaf(x2, b2f_lo(uw.y), a);
        a = fmaf(x3, b2f_hi(uw.y), a);
        a = fmaf(x4, b2f_lo(uw.z), a);
        a = fmaf(x5, b2f_hi(uw.z), a);
        a = fmaf(x6, b2f_lo(uw.w), a);
        a = fmaf(x7, b2f_hi(uw.w), a);
        acc[ei] = a;
      }
    }
  }
  #pragma unroll
  for (int ei = 0; ei < 5; ++ei) {
    int e = c + (ei << 4);
    if (e < 72) out[(r0 + r) * 72 + e] = acc[ei] + db[e];
  }
}

// ---------------------------------------------------------------------------
extern "C" void kernel_launch(void* const* d_in, const int* in_sizes, int n_in,
                              void* d_out, int out_size, void* d_ws, size_t ws_size,
                              hipStream_t stream) {
  const float* src  = (const float*)d_in[0];   // [1024,16,72]
  const float* tgt  = (const float*)d_in[1];   // [1024,12,72]
  const float* encW = (const float*)d_in[2];   // [3,64]
  const float* encb = (const float*)d_in[3];   // [64]
  const float* sWl  = (const float*)d_in[4];   // [8,64,64]
  const float* sbl  = (const float*)d_in[5];   // [8,64]
  const float* sWr  = (const float*)d_in[6];   // [8,64,64]
  const float* gw   = (const float*)d_in[7];   // [3,1,64]
  const float* gb   = (const float*)d_in[8];   // [4,1,64]
  const float* dW   = (const float*)d_in[9];   // [1536,72]
  const float* db   = (const float*)d_in[10];  // [72]
  float* out = (float*)d_out;

  unsigned short* obuf  = (unsigned short*)d_ws;        // 12288*1536 bf16 = 36.75 MB
  unsigned short* Wfrag = obuf + (size_t)12288 * 1536;  // 65536 bf16
  unsigned short* dWT   = Wfrag + 65536;                // 110592 bf16
  float*          biasv = (float*)(dWT + 110592);       // 256 f32 (16B-aligned)

  prep2_kernel<<<689, 256, 0, stream>>>(sWl, sbl, sWr, gb, dW, Wfrag, biasv, dWT);
  mono_kernel<<<1024, 512, 0, stream>>>(src, tgt, encW, encb, gw, Wfrag, biasv, obuf);
  dec2_kernel<<<768, 256, 0, stream>>>(obuf, dWT, db, out);
}

// Round 3
// 556.531 us; speedup vs baseline: 4.2210x; 1.0724x over previous
//
#include <hip/hip_runtime.h>

// ---------------------------------------------------------------------------
// SAGE-GCN LSTM, N=1024, J=24, D=64.  R3 design:
//  mono: 256 blocks (1/CU) x 512 thr (8 waves), all 24 cells in-kernel.
//   GEMM per step: pre^T[256 x 96] = Wcat^T[256x256] @ v^T[256x96]
//   A = W in VGPRs (gate-interleaved M so epilogue is lane-local),
//   B = v built in LDS fragment layout. W_M=4: each vfrag feeds 2 MFMAs.
//   Waves: wm=w&3 owns d-slice [16wm,16wm+16); wnt=w>>2: {nt0,nt1} / {nt2}.
//  dec: MFMA, 4-wave K-split + LDS reduce.
// ---------------------------------------------------------------------------

typedef __bf16 bf16x8 __attribute__((ext_vector_type(8)));
typedef float f32x16 __attribute__((ext_vector_type(16)));

__constant__ int c_nbr[24][5] = {
  {0,1,2,3,-1},  {1,0,4,-1,-1}, {2,0,5,-1,-1}, {3,0,6,-1,-1},
  {4,1,7,-1,-1}, {5,2,8,-1,-1}, {6,3,9,-1,-1}, {7,4,10,-1,-1},
  {8,5,11,-1,-1},{9,6,12,13,14},{10,7,-1,-1,-1},{11,8,-1,-1,-1},
  {12,9,15,-1,-1},{13,9,16,-1,-1},{14,9,17,-1,-1},{15,12,-1,-1,-1},
  {16,13,18,-1,-1},{17,14,19,-1,-1},{18,16,20,-1,-1},{19,17,21,-1,-1},
  {20,18,22,-1,-1},{21,19,23,-1,-1},{22,20,-1,-1,-1},{23,21,-1,-1,-1}
};
__constant__ float c_invdeg[24] = {
  0.25f, 1.f/3.f, 1.f/3.f, 1.f/3.f, 1.f/3.f, 1.f/3.f, 1.f/3.f, 1.f/3.f,
  1.f/3.f, 0.2f, 0.5f, 0.5f, 1.f/3.f, 1.f/3.f, 1.f/3.f, 0.5f,
  1.f/3.f, 1.f/3.f, 1.f/3.f, 1.f/3.f, 1.f/3.f, 1.f/3.f, 0.5f, 0.5f
};

__device__ __forceinline__ unsigned short f2b(float f) {   // fp32->bf16 RNE
  unsigned int u = __float_as_uint(f);
  u += 0x7fffu + ((u >> 16) & 1u);
  return (unsigned short)(u >> 16);
}
__device__ __forceinline__ unsigned pk2(float a, float b) {
  return (unsigned)f2b(a) | ((unsigned)f2b(b) << 16);
}
__device__ __forceinline__ float b2f_lo(unsigned u) { return __uint_as_float(u << 16); }
__device__ __forceinline__ float b2f_hi(unsigned u) { return __uint_as_float(u & 0xffff0000u); }
__device__ __forceinline__ float sigm_(float x) { return 1.0f / (1.0f + __expf(-x)); }
__device__ __forceinline__ float tanh_(float x) { return 2.0f / (1.0f + __expf(-2.0f * x)) - 1.0f; }

// ---------------------------------------------------------------------------
// prep: Wfrag = A-operand frag layout (gate-interleaved M), biasv, dec B-frags.
//  m32 (col within M-tile mt): gate g = m32&3, d = mt*8 + (m32>>2)
//  k = t*16 + (lane>>5)*8 + i; q=k>>6: q0 Wl[2g], q1 Wr[2g], q2 Wl[2g+1], q3 Wr[2g+1]
// ---------------------------------------------------------------------------
__global__ void prep3_kernel(const float* __restrict__ sWl, const float* __restrict__ sbl,
                             const float* __restrict__ sWr, const float* __restrict__ gb,
                             const float* __restrict__ dW,
                             unsigned short* __restrict__ Wfrag,
                             float* __restrict__ biasv,
                             unsigned short* __restrict__ Bdec)
{
  int id = blockIdx.x * 256 + threadIdx.x;          // 213248 total
  if (id < 65536) {                                  // Wfrag [mt][t][lane][8]
    int i = id & 7, l = (id >> 3) & 63, t = (id >> 9) & 15, mt = id >> 13;
    int m32 = l & 31;
    int g = m32 & 3, d = mt * 8 + (m32 >> 2);
    int k = t * 16 + ((l >> 5) << 3) + i;
    int q = k >> 6, kk = k & 63;
    const float* Ws = (q & 1) ? sWr : sWl;
    Wfrag[id] = f2b(Ws[((2 * g + (q >> 1)) * 64 + kk) * 64 + d]);
  } else if (id < 65792) {                           // biasv[mt*32 + m32]
    int c = id - 65536;
    int mt = c >> 5, m32 = c & 31;
    int g = m32 & 3, d = mt * 8 + (m32 >> 2);
    biasv[c] = sbl[(2 * g) * 64 + d] + sbl[(2 * g + 1) * 64 + d] + gb[g * 64 + d];
  } else {                                           // Bdec [nt][96 t][lane][8]
    int p = id - 65792;                              // < 147456
    int i = p & 7, l = (p >> 3) & 63;
    int rem = p >> 9;                                // nt*96 + t
    int nt = rem / 96, t = rem - nt * 96;
    int e = nt * 32 + (l & 31);
    int k = t * 16 + ((l >> 5) << 3) + i;
    Bdec[p] = (e < 72) ? f2b(dW[k * 72 + e]) : (unsigned short)0;
  }
}

// ---------------------------------------------------------------------------
// mono: all 24 cells for 4 batch elements per block.
// ---------------------------------------------------------------------------
__global__ __launch_bounds__(512) void mono3_kernel(
    const float* __restrict__ src, const float* __restrict__ tgt,
    const float* __restrict__ encW, const float* __restrict__ encb,
    const float* __restrict__ gw,
    const unsigned short* __restrict__ Wfrag,
    const float* __restrict__ biasv,
    unsigned short* __restrict__ obuf)
{
  __shared__ __align__(16) unsigned short Bf[3 * 16 * 64 * 8];  // 48 KB v-frags
  __shared__ __align__(16) unsigned short xs[96 * 64];          // 12 KB (swizzled)
  __shared__ __align__(16) unsigned short hs[96 * 64];          // 12 KB (swizzled)

  const int tid = threadIdx.x;
  const int n4 = blockIdx.x * 4;
  const int w = tid >> 6, l = tid & 63;
  const int wm = w & 3, wnt = w >> 2;
  const int l31 = l & 31, hi = l >> 5;

  // ---- persistent W: 2 M-tiles x 16 k-steps = 128 VGPR -------------------
  bf16x8 W0[16], W1[16];
  {
    const bf16x8* p0 = reinterpret_cast<const bf16x8*>(Wfrag) + ((2 * wm) * 16) * 64 + l;
    const bf16x8* p1 = reinterpret_cast<const bf16x8*>(Wfrag) + ((2 * wm + 1) * 16) * 64 + l;
    #pragma unroll
    for (int t = 0; t < 16; ++t) { W0[t] = p0[t * 64]; W1[t] = p1[t * 64]; }
  }
  // ---- bias (bf16-packed, per acc-reg pair) ------------------------------
  unsigned bias_u[2][8];
  #pragma unroll
  for (int mtl = 0; mtl < 2; ++mtl) {
    #pragma unroll
    for (int p = 0; p < 8; ++p) {
      int r0 = 2 * p, r1 = 2 * p + 1;
      int m0 = (r0 & 3) + 8 * (r0 >> 2) + 4 * hi;
      int m1 = (r1 & 3) + 8 * (r1 >> 2) + 4 * hi;
      bias_u[mtl][p] = pk2(biasv[(2 * wm + mtl) * 32 + m0], biasv[(2 * wm + mtl) * 32 + m1]);
    }
  }
  // ---- gate_w (bf16-packed per (gate,u): lo=mtl0, hi=mtl1) ---------------
  unsigned gw_u[3][4];
  #pragma unroll
  for (int g = 0; g < 3; ++g) {
    #pragma unroll
    for (int u = 0; u < 4; ++u) {
      int d0 = (2 * wm) * 8 + 2 * u + hi;
      gw_u[g][u] = pk2(gw[g * 64 + d0], gw[g * 64 + d0 + 8]);
    }
  }

  float creg[16];
  #pragma unroll
  for (int i = 0; i < 16; ++i) creg[i] = 0.0f;

  // zero h state
  for (int i = tid; i < 3072; i += 512) reinterpret_cast<unsigned*>(hs)[i] = 0u;

  auto enc_to_xs = [&](const float* base, int stride) {
    #pragma unroll
    for (int ii = 0; ii < 12; ++ii) {
      int idx = tid + ii * 512;                 // < 6144
      int ns = idx / 1536;
      int r2 = idx - ns * 1536;
      int jj = r2 >> 6, dd = r2 & 63;
      const float* f = base + (size_t)ns * stride + jj * 3;
      float v = encb[dd] + f[0] * encW[dd] + f[1] * encW[64 + dd] + f[2] * encW[128 + dd];
      int row = ns * 24 + jj;
      xs[row * 64 + (((dd >> 3) ^ (row & 7)) << 3) + (dd & 7)] = f2b(fmaxf(v, 0.0f));
    }
  };

  enc_to_xs(src + ((size_t)n4 * 16 + 4) * 72, 16 * 72);   // warm-up frame 4
  __syncthreads();

  for (int step = 0; step < 24; ++step) {
    if (step == 12) {                          // decode init: re-encode tgt[:,0]
      enc_to_xs(tgt + (size_t)n4 * 12 * 72, 12 * 72);
      __syncthreads();
    }

    // ---- v-build: B-fragments [nt][t][lane][8] ---------------------------
    #pragma unroll
    for (int it = 0; it < 3; ++it) {           // agg sections q0 (x), q2 (h)
      int job = tid + it * 512;                // < 1536
      int sec = (job >= 768) ? 1 : 0;
      int rem = job - sec * 768;
      int Mrow = rem >> 3, ch = rem & 7;
      const unsigned short* sb = sec ? hs : xs;
      int ns = (Mrow * 2731) >> 16;
      int jj = Mrow - ns * 24;
      float s0 = 0, s1 = 0, s2 = 0, s3 = 0, s4 = 0, s5 = 0, s6 = 0, s7 = 0;
      #pragma unroll
      for (int m = 0; m < 5; ++m) {
        int nb = c_nbr[jj][m];
        if (nb >= 0) {
          int nr = ns * 24 + nb;
          uint4 u = *reinterpret_cast<const uint4*>(sb + nr * 64 + ((ch ^ (nr & 7)) << 3));
          s0 += b2f_lo(u.x); s1 += b2f_hi(u.x);
          s2 += b2f_lo(u.y); s3 += b2f_hi(u.y);
          s4 += b2f_lo(u.z); s5 += b2f_hi(u.z);
          s6 += b2f_lo(u.w); s7 += b2f_hi(u.w);
        }
      }
      float sc = c_invdeg[jj];
      uint4 o;
      o.x = pk2(s0 * sc, s1 * sc); o.y = pk2(s2 * sc, s3 * sc);
      o.z = pk2(s4 * sc, s5 * sc); o.w = pk2(s6 * sc, s7 * sc);
      int kb = sec * 128 + ch * 8;
      int t = kb >> 4, h2 = ch & 1;
      *reinterpret_cast<uint4*>(Bf + ((((Mrow >> 5) * 16 + t) * 64) + (Mrow & 31) + (h2 << 5)) * 8) = o;
    }
    #pragma unroll
    for (int it = 0; it < 3; ++it) {           // copy sections q1 (x), q3 (h)
      int job = tid + it * 512;
      int sec = (job >= 768) ? 1 : 0;
      int rem = job - sec * 768;
      int Mrow = rem >> 3, ch = rem & 7;
      const unsigned short* sb = sec ? hs : xs;
      uint4 u = *reinterpret_cast<const uint4*>(sb + Mrow * 64 + ((ch ^ (Mrow & 7)) << 3));
      int kb = 64 + sec * 128 + ch * 8;
      int t = kb >> 4, h2 = ch & 1;
      *reinterpret_cast<uint4*>(Bf + ((((Mrow >> 5) * 16 + t) * 64) + (Mrow & 31) + (h2 << 5)) * 8) = u;
    }
    __syncthreads();

    // ---- GEMM + lane-local epilogue --------------------------------------
#define EPI_HALF(NT, CB, A, MTL)                                               \
    {                                                                          \
      const int mt = 2 * wm + (MTL);                                           \
      int row = (NT) * 32 + l31;                                               \
      int ns = (row * 2731) >> 16;                                             \
      int jj = row - ns * 24;                                                  \
      _Pragma("unroll")                                                        \
      for (int u = 0; u < 4; ++u) {                                            \
        float cv = creg[(CB) + (MTL) * 4 + u];                                 \
        float g0 = (MTL) ? b2f_hi(gw_u[0][u]) : b2f_lo(gw_u[0][u]);            \
        float g1 = (MTL) ? b2f_hi(gw_u[1][u]) : b2f_lo(gw_u[1][u]);            \
        float g2 = (MTL) ? b2f_hi(gw_u[2][u]) : b2f_lo(gw_u[2][u]);            \
        float I = sigm_(A[4 * u + 0] + g0 * cv);                               \
        float F = sigm_(A[4 * u + 1] + g1 * cv);                               \
        float T = tanh_(A[4 * u + 2]);                                         \
        float cn = F * cv + I * T;                                             \
        float O = sigm_(A[4 * u + 3] + g2 * cn);                               \
        float h = O * tanh_(cn);                                               \
        creg[(CB) + (MTL) * 4 + u] = cn;                                       \
        int d7 = 2 * u + hi;                                                   \
        int off = row * 64 + ((mt ^ (row & 7)) << 3) + d7;                     \
        xs[off] = f2b(O);                                                      \
        hs[off] = f2b(h);                                                      \
        if (step >= 12)                                                        \
          obuf[((size_t)((n4 + ns) * 12 + (step - 12))) * 1536 + jj * 64 + mt * 8 + d7] = f2b(O); \
      }                                                                        \
    }

#define ROUND(NT, CB)                                                          \
    {                                                                          \
      f32x16 a0, a1;                                                           \
      _Pragma("unroll")                                                        \
      for (int p = 0; p < 8; ++p) {                                            \
        a0[2 * p] = b2f_lo(bias_u[0][p]); a0[2 * p + 1] = b2f_hi(bias_u[0][p]);\
        a1[2 * p] = b2f_lo(bias_u[1][p]); a1[2 * p + 1] = b2f_hi(bias_u[1][p]);\
      }                                                                        \
      _Pragma("unroll")                                                        \
      for (int t = 0; t < 16; ++t) {                                           \
        bf16x8 vf = *reinterpret_cast<const bf16x8*>(Bf + (((NT) * 16 + t) * 64 + l) * 8); \
        a0 = __builtin_amdgcn_mfma_f32_32x32x16_bf16(W0[t], vf, a0, 0, 0, 0);  \
        a1 = __builtin_amdgcn_mfma_f32_32x32x16_bf16(W1[t], vf, a1, 0, 0, 0);  \
      }                                                                        \
      EPI_HALF(NT, CB, a0, 0)                                                  \
      EPI_HALF(NT, CB, a1, 1)                                                  \
    }

    if (wnt == 0) { ROUND(0, 0) ROUND(1, 8) }
    else          { ROUND(2, 0) }
#undef ROUND
#undef EPI_HALF
    __syncthreads();
  }
}

// ---------------------------------------------------------------------------
// dec: out[row][e] = O[row,:] . decW[:,e] + db[e]; rows = n*12+ts.
// block: 32 rows, 4 waves K-split (384 each), 3 col-tiles, LDS reduce.
// ---------------------------------------------------------------------------
__global__ __launch_bounds__(256) void dec3_kernel(
    const unsigned short* __restrict__ obuf,
    const unsigned short* __restrict__ Bdec,
    const float* __restrict__ db,
    float* __restrict__ out)
{
  __shared__ float part[4 * 3 * 64 * 16];    // 48 KB
  const int tid = threadIdx.x;
  const int w = tid >> 6, l = tid & 63;
  const int l31 = l & 31, hi = l >> 5;
  const int r0 = blockIdx.x * 32;

  f32x16 a0, a1, a2;
  #pragma unroll
  for (int r = 0; r < 16; ++r) { a0[r] = 0.f; a1[r] = 0.f; a2[r] = 0.f; }

  const unsigned short* Ap = obuf + (size_t)(r0 + l31) * 1536 + hi * 8;
  #pragma unroll 4
  for (int tt = 0; tt < 24; ++tt) {
    int kt = w * 24 + tt;
    bf16x8 av = *reinterpret_cast<const bf16x8*>(Ap + kt * 16);
    bf16x8 b0 = *reinterpret_cast<const bf16x8*>(Bdec + ((0 * 96 + kt) * 64 + l) * 8);
    bf16x8 b1 = *reinterpret_cast<const bf16x8*>(Bdec + ((1 * 96 + kt) * 64 + l) * 8);
    bf16x8 b2 = *reinterpret_cast<const bf16x8*>(Bdec + ((2 * 96 + kt) * 64 + l) * 8);
    a0 = __builtin_amdgcn_mfma_f32_32x32x16_bf16(av, b0, a0, 0, 0, 0);
    a1 = __builtin_amdgcn_mfma_f32_32x32x16_bf16(av, b1, a1, 0, 0, 0);
    a2 = __builtin_amdgcn_mfma_f32_32x32x16_bf16(av, b2, a2, 0, 0, 0);
  }
  #pragma unroll
  for (int r = 0; r < 16; ++r) {
    part[((w * 3 + 0) * 64 + l) * 16 + r] = a0[r];
    part[((w * 3 + 1) * 64 + l) * 16 + r] = a1[r];
    part[((w * 3 + 2) * 64 + l) * 16 + r] = a2[r];
  }
  __syncthreads();

  // reduce 4 K-partials; thread -> (row = tid>>3, e = (tid&7)*12 + 0..11)
  int row = tid >> 3;
  int hi2 = (row >> 2) & 1;
  int rr = 4 * (row >> 3) + (row & 3);
  #pragma unroll
  for (int ei = 0; ei < 12; ++ei) {
    int e = (tid & 7) * 12 + ei;
    if (e < 72) {
      int nt = e >> 5, e32 = e & 31;
      float s = db[e];
      #pragma unroll
      for (int w2 = 0; w2 < 4; ++w2)
        s += part[((w2 * 3 + nt) * 64 + e32 + 32 * hi2) * 16 + rr];
      out[(size_t)(r0 + row) * 72 + e] = s;
    }
  }
}

// ---------------------------------------------------------------------------
extern "C" void kernel_launch(void* const* d_in, const int* in_sizes, int n_in,
                              void* d_out, int out_size, void* d_ws, size_t ws_size,
                              hipStream_t stream) {
  const float* src  = (const float*)d_in[0];   // [1024,16,72]
  const float* tgt  = (const float*)d_in[1];   // [1024,12,72]
  const float* encW = (const float*)d_in[2];   // [3,64]
  const float* encb = (const float*)d_in[3];   // [64]
  const float* sWl  = (const float*)d_in[4];   // [8,64,64]
  const float* sbl  = (const float*)d_in[5];   // [8,64]
  const float* sWr  = (const float*)d_in[6];   // [8,64,64]
  const float* gw   = (const float*)d_in[7];   // [3,1,64]
  const float* gb   = (const float*)d_in[8];   // [4,1,64]
  const float* dW   = (const float*)d_in[9];   // [1536,72]
  const float* db   = (const float*)d_in[10];  // [72]
  float* out = (float*)d_out;

  unsigned short* obuf  = (unsigned short*)d_ws;        // 12288*1536 bf16
  unsigned short* Wfrag = obuf + (size_t)12288 * 1536;  // 65536 bf16
  unsigned short* Bdec  = Wfrag + 65536;                // 147456 bf16
  float*          biasv = (float*)(Bdec + 147456);      // 256 f32

  prep3_kernel<<<833, 256, 0, stream>>>(sWl, sbl, sWr, gb, dW, Wfrag, biasv, Bdec);
  mono3_kernel<<<256, 512, 0, stream>>>(src, tgt, encW, encb, gw, Wfrag, biasv, obuf);
  dec3_kernel<<<384, 256, 0, stream>>>(obuf, Bdec, db, out);
}